// Round 5
// baseline (137.603 us; speedup 1.0000x reference)
//
#include <hip/hip_runtime.h>
#include <hip/hip_bf16.h>

typedef float  f32x4 __attribute__((ext_vector_type(4)));
typedef float  f32x8 __attribute__((ext_vector_type(8)));
typedef short  s8v   __attribute__((ext_vector_type(8)));
typedef __bf16 b8v   __attribute__((ext_vector_type(8)));

#define T_DIM  2048
#define C_DIM  1024
#define HS_DIM 128
#define NBATCH 4

// ---------- helpers ----------

static __device__ __forceinline__ b8v ldb8(const unsigned short* p) {
  return __builtin_bit_cast(b8v, *reinterpret_cast<const s8v*>(p));
}

// packed f32x8 -> bf16x8 (compiler emits v_cvt_pk_bf16_f32)
static __device__ __forceinline__ b8v cvt8(f32x8 v) {
  b8v r;
#pragma unroll
  for (int i = 0; i < 8; ++i) r[i] = (__bf16)v[i];
  return r;
}

static __device__ __forceinline__ unsigned short bfu(float f) {
  __bf16 h = (__bf16)f;
  return __builtin_bit_cast(unsigned short, h);
}

static __device__ __forceinline__ f32x4 mfma16(b8v a, b8v b, f32x4 c) {
  return __builtin_amdgcn_mfma_f32_16x16x32_bf16(a, b, c, 0, 0, 0);
}

// ---------- kernel 0: W -> Wt bf16 transposed [3][128][1024] ----------
__global__ __launch_bounds__(256) void wconv(const float* __restrict__ Wq,
                                             const float* __restrict__ Wk,
                                             const float* __restrict__ Wv,
                                             unsigned short* __restrict__ Wt) {
  __shared__ float lds[64][65];
  const int m  = blockIdx.z;
  const int c0 = blockIdx.x * 64;
  const int h0 = blockIdx.y * 64;
  const float* W = (m == 0) ? Wq : (m == 1) ? Wk : Wv;

  const int cl = threadIdx.x >> 4;         // 0..15
  const int h4 = (threadIdx.x & 15) * 4;   // 0..60
#pragma unroll
  for (int i = 0; i < 4; ++i) {
    int c = cl + i * 16;
    float4 v = *reinterpret_cast<const float4*>(W + (c0 + c) * 128 + h0 + h4);
    lds[c][h4] = v.x; lds[c][h4 + 1] = v.y;
    lds[c][h4 + 2] = v.z; lds[c][h4 + 3] = v.w;
  }
  __syncthreads();
  const int hl = threadIdx.x >> 2;         // 0..63
  const int cs = (threadIdx.x & 3) * 16;   // 0..48
  s8v o0, o1;
#pragma unroll
  for (int i = 0; i < 8; ++i) o0[i] = (short)bfu(lds[cs + i][hl]);
#pragma unroll
  for (int i = 0; i < 8; ++i) o1[i] = (short)bfu(lds[cs + 8 + i][hl]);
  unsigned short* dst = Wt + (m * 128 + h0 + hl) * C_DIM + c0 + cs;
  *reinterpret_cast<s8v*>(dst) = o0;
  *reinterpret_cast<s8v*>(dst + 8) = o1;
}

// ---------- kernel 1: q/k/v projection, register-pipelined ----------
// grid (256, 3) x 256 thr (4 waves). Block: 32 rows x 128 cols of mat m.
// Wave (wr,wc): rows r0+wr*16, cols wc*64. Full K unroll, cur/next dbuf:
// all 12 loads of step i+1 in flight while step i computes.
__global__ __launch_bounds__(256) void proj(const float* __restrict__ x,
                                            const unsigned short* __restrict__ Wt,
                                            unsigned short* __restrict__ q,
                                            unsigned short* __restrict__ k,
                                            unsigned short* __restrict__ vt) {
  __shared__ __align__(16) unsigned short stage[5120];  // max(32*136, 128*40)

  const int w   = threadIdx.x >> 6;
  const int lid = threadIdx.x & 63;
  const int lr  = lid & 15;
  const int g   = lid >> 4;
  const int wr  = w >> 1;
  const int wc  = w & 1;
  const int m   = blockIdx.y;
  const int r0  = blockIdx.x * 32 + wr * 16;

  f32x4 acc[4] = {};

  const float* xrow = x + (r0 + lr) * C_DIM;
  const unsigned short* wbase = Wt + (m * 128 + wc * 64) * C_DIM;

  // cur / next register buffers
  f32x8 xa_c, xb_c;
  s8v bq_c[4][2];

  xa_c = *reinterpret_cast<const f32x8*>(xrow + g * 8);
  xb_c = *reinterpret_cast<const f32x8*>(xrow + 32 + g * 8);
#pragma unroll
  for (int hf = 0; hf < 4; ++hf) {
    const unsigned short* bp = wbase + (hf * 16 + lr) * C_DIM + g * 8;
    bq_c[hf][0] = *reinterpret_cast<const s8v*>(bp);
    bq_c[hf][1] = *reinterpret_cast<const s8v*>(bp + 32);
  }

#pragma unroll
  for (int i = 0; i < 16; ++i) {
    f32x8 xa_n = {}, xb_n = {};
    s8v bq_n[4][2] = {};
    if (i < 15) {
      const int kn = (i + 1) * 64;
      xa_n = *reinterpret_cast<const f32x8*>(xrow + kn + g * 8);
      xb_n = *reinterpret_cast<const f32x8*>(xrow + kn + 32 + g * 8);
#pragma unroll
      for (int hf = 0; hf < 4; ++hf) {
        const unsigned short* bp = wbase + (hf * 16 + lr) * C_DIM + kn + g * 8;
        bq_n[hf][0] = *reinterpret_cast<const s8v*>(bp);
        bq_n[hf][1] = *reinterpret_cast<const s8v*>(bp + 32);
      }
    }

    b8v af0 = cvt8(xa_c);
    b8v af1 = cvt8(xb_c);
#pragma unroll
    for (int hf = 0; hf < 4; ++hf) {
      acc[hf] = mfma16(af0, __builtin_bit_cast(b8v, bq_c[hf][0]), acc[hf]);
      acc[hf] = mfma16(af1, __builtin_bit_cast(b8v, bq_c[hf][1]), acc[hf]);
    }

    xa_c = xa_n; xb_c = xb_n;
#pragma unroll
    for (int hf = 0; hf < 4; ++hf) {
      bq_c[hf][0] = bq_n[hf][0];
      bq_c[hf][1] = bq_n[hf][1];
    }
  }

  // ----- epilogue -----
  if (m < 2) {
#pragma unroll
    for (int hf = 0; hf < 4; ++hf)
#pragma unroll
      for (int j = 0; j < 4; ++j)
        stage[(wr * 16 + 4 * g + j) * 136 + wc * 64 + hf * 16 + lr] =
            bfu(acc[hf][j]);
    __syncthreads();
    unsigned short* dst = (m == 0) ? q : k;
#pragma unroll
    for (int c = 0; c < 2; ++c) {
      int chunk = c * 256 + threadIdx.x;  // 512 chunks of 8: 32 rows x 16
      int row = chunk >> 4, col8 = chunk & 15;
      s8v v8 = *reinterpret_cast<const s8v*>(&stage[row * 136 + col8 * 8]);
      *reinterpret_cast<s8v*>(&dst[(blockIdx.x * 32 + row) * 128 + col8 * 8]) = v8;
    }
  } else {
#pragma unroll
    for (int hf = 0; hf < 4; ++hf)
#pragma unroll
      for (int j = 0; j < 4; ++j)
        stage[(wc * 64 + hf * 16 + lr) * 40 + wr * 16 + 4 * g + j] =
            bfu(acc[hf][j]);
    __syncthreads();
    int b = blockIdx.x >> 6;
    int tbase = (blockIdx.x & 63) * 32;
#pragma unroll
    for (int c = 0; c < 2; ++c) {
      int chunk = c * 256 + threadIdx.x;  // 512 chunks: 128 h x 4 t-chunks
      int h = chunk >> 2, t8 = chunk & 3;
      s8v v8 = *reinterpret_cast<const s8v*>(&stage[h * 40 + t8 * 8]);
      *reinterpret_cast<s8v*>(&vt[(b * 128 + h) * T_DIM + tbase + t8 * 8]) = v8;
    }
  }
}

// ---------- kernel 2: flash attention, no-max softmax, register-pipelined ----------
// grid (128, 4): x = q-tile of 16 rows, y = batch. 8 waves, wave w handles
// kv range w*256 .. +256 in 8 steps of 32. K and V frags double-buffered in
// registers: 16 loads of step i+1 in flight across step i's compute.
__global__ __launch_bounds__(512) void attn(
    const unsigned short* __restrict__ q, const unsigned short* __restrict__ k,
    const unsigned short* __restrict__ vt, float* __restrict__ out) {
  __shared__ __align__(16) unsigned short pbuf[8][16 * 40];  // 10 KB
  __shared__ float lbuf[8][16];                              // 0.5 KB
  __shared__ __align__(16) float obuf[7][16][128];           // 56 KB

  const int w   = threadIdx.x >> 6;
  const int lid = threadIdx.x & 63;
  const int lr  = lid & 15;
  const int g   = lid >> 4;
  const int b   = blockIdx.y;
  const int t0  = blockIdx.x * 16;

  const unsigned short* qp = q + (b * T_DIM + t0) * 128;
  const unsigned short* kp = k + (b * T_DIM + w * 256) * 128;
  const unsigned short* vp = vt + b * 128 * T_DIM + w * 256;

  // hoist Q fragments (16 rows x 128)
  b8v aq[4];
#pragma unroll
  for (int kf = 0; kf < 4; ++kf)
    aq[kf] = ldb8(&qp[lr * 128 + kf * 32 + g * 8]);

  float lsum[4] = {0.0f, 0.0f, 0.0f, 0.0f};
  f32x4 of[8] = {};

  const float scale = 0.08838834764831845f;  // 128^-0.5
  unsigned short* pb = &pbuf[w][0];

  // preload step 0
  s8v kc[4][2], vc[8];
#pragma unroll
  for (int kf = 0; kf < 4; ++kf)
#pragma unroll
    for (int c = 0; c < 2; ++c)
      kc[kf][c] = *reinterpret_cast<const s8v*>(
          &kp[(c * 16 + lr) * 128 + kf * 32 + g * 8]);
#pragma unroll
  for (int hf = 0; hf < 8; ++hf)
    vc[hf] = *reinterpret_cast<const s8v*>(&vp[(hf * 16 + lr) * T_DIM + g * 8]);

#pragma unroll
  for (int i = 0; i < 8; ++i) {
    s8v kn[4][2] = {};
    s8v vn[8] = {};
    if (i < 7) {
      const int kvn = (i + 1) * 32;
#pragma unroll
      for (int kf = 0; kf < 4; ++kf)
#pragma unroll
        for (int c = 0; c < 2; ++c)
          kn[kf][c] = *reinterpret_cast<const s8v*>(
              &kp[(kvn + c * 16 + lr) * 128 + kf * 32 + g * 8]);
#pragma unroll
      for (int hf = 0; hf < 8; ++hf)
        vn[hf] = *reinterpret_cast<const s8v*>(
            &vp[(hf * 16 + lr) * T_DIM + kvn + g * 8]);
    }

    // ---- S = Q K^T for 16q x 32kv ----
    f32x4 s0 = {}, s1 = {};
#pragma unroll
    for (int kf = 0; kf < 4; ++kf) {
      s0 = mfma16(aq[kf], __builtin_bit_cast(b8v, kc[kf][0]), s0);
      s1 = mfma16(aq[kf], __builtin_bit_cast(b8v, kc[kf][1]), s1);
    }

    // ---- p = exp(s*scale - 4); partial row sums; P -> LDS ----
#pragma unroll
    for (int j = 0; j < 4; ++j) {
      float p0 = __expf(s0[j] * scale - 4.0f);
      float p1 = __expf(s1[j] * scale - 4.0f);
      lsum[j] += p0 + p1;
      pb[(4 * g + j) * 40 + lr]      = bfu(p0);
      pb[(4 * g + j) * 40 + 16 + lr] = bfu(p1);
    }
    asm volatile("s_waitcnt lgkmcnt(0)" ::: "memory");

    // ---- O += P V ----
    b8v pa = ldb8(&pb[lr * 40 + g * 8]);
#pragma unroll
    for (int hf = 0; hf < 8; ++hf)
      of[hf] = mfma16(pa, __builtin_bit_cast(b8v, vc[hf]), of[hf]);

    // swap
#pragma unroll
    for (int kf = 0; kf < 4; ++kf) {
      kc[kf][0] = kn[kf][0];
      kc[kf][1] = kn[kf][1];
    }
#pragma unroll
    for (int hf = 0; hf < 8; ++hf) vc[hf] = vn[hf];
  }

  // ---- reduce l over the 16 kv-lanes ----
#pragma unroll
  for (int j = 0; j < 4; ++j) {
    float r = lsum[j];
    r += __shfl_xor(r, 1);
    r += __shfl_xor(r, 2);
    r += __shfl_xor(r, 4);
    r += __shfl_xor(r, 8);
    lsum[j] = r;
  }

  // ---- merge the eight kv partials (plain sums, common scale) ----
  if (w != 0) {
    if (lr == 0) {
#pragma unroll
      for (int j = 0; j < 4; ++j) lbuf[w][4 * g + j] = lsum[j];
    }
#pragma unroll
    for (int hf = 0; hf < 8; ++hf)
#pragma unroll
      for (int j = 0; j < 4; ++j)
        obuf[w - 1][4 * g + j][hf * 16 + lr] = of[hf][j];
  }
  __syncthreads();
  if (w == 0) {
    float inv[4];
#pragma unroll
    for (int j = 0; j < 4; ++j) {
      int row = 4 * g + j;
      float l = lsum[j];
#pragma unroll
      for (int i = 1; i < 8; ++i) l += lbuf[i][row];
      inv[j] = 1.0f / l;
    }
    float* op = out + (b * T_DIM + t0) * 128;
#pragma unroll
    for (int hf = 0; hf < 8; ++hf)
#pragma unroll
      for (int j = 0; j < 4; ++j) {
        int row = 4 * g + j, col = hf * 16 + lr;
        float val = of[hf][j];
#pragma unroll
        for (int i = 1; i < 8; ++i) val += obuf[i - 1][row][col];
        op[row * 128 + col] = val * inv[j];
      }
  }
}

// ---------- launcher ----------
extern "C" void kernel_launch(void* const* d_in, const int* in_sizes, int n_in,
                              void* d_out, int out_size, void* d_ws,
                              size_t ws_size, hipStream_t stream) {
  const float* x  = (const float*)d_in[0];
  const float* Wk = (const float*)d_in[1];
  const float* Wq = (const float*)d_in[2];
  const float* Wv = (const float*)d_in[3];
  float* out = (float*)d_out;

  char* ws = (char*)d_ws;
  unsigned short* Wt = (unsigned short*)ws;                      // 0.75 MB
  unsigned short* qb = (unsigned short*)(ws + (1u << 20));       // 2 MB
  unsigned short* kb = (unsigned short*)(ws + 3u * (1u << 20));  // 2 MB
  unsigned short* vtb = (unsigned short*)(ws + 5u * (1u << 20)); // 2 MB

  wconv<<<dim3(16, 2, 3), dim3(256), 0, stream>>>(Wq, Wk, Wv, Wt);
  proj<<<dim3(256, 3), dim3(256), 0, stream>>>(x, Wt, qb, kb, vtb);
  attn<<<dim3(128, 4), dim3(512), 0, stream>>>(qb, kb, vtb, out);
}

// Round 6
// 65.461 us; speedup vs baseline: 2.1021x; 2.1021x over previous
//
#include <hip/hip_runtime.h>
#include <hip/hip_bf16.h>

typedef float  f32x4 __attribute__((ext_vector_type(4)));
typedef float  f32x8 __attribute__((ext_vector_type(8)));
typedef short  s8v   __attribute__((ext_vector_type(8)));
typedef __bf16 b8v   __attribute__((ext_vector_type(8)));
typedef unsigned int u32;
typedef unsigned short ushort;

#define T_DIM  2048
#define C_DIM  1024

// ---------- helpers ----------

typedef const __attribute__((address_space(1))) u32 gu32;
typedef __attribute__((address_space(3))) u32 lu32;

// async global->LDS, 16B per lane; LDS dest = base + lane*16 (wave-uniform base)
static __device__ __forceinline__ void glds16(const void* g, void* l) {
  __builtin_amdgcn_global_load_lds((gu32*)g, (lu32*)l, 16, 0, 0);
}

static __device__ __forceinline__ b8v ldb8(const ushort* p) {
  return __builtin_bit_cast(b8v, *reinterpret_cast<const s8v*>(p));
}

static __device__ __forceinline__ b8v cvt8(f32x8 v) {
  b8v r;
#pragma unroll
  for (int i = 0; i < 8; ++i) r[i] = (__bf16)v[i];
  return r;
}

static __device__ __forceinline__ ushort bfu(float f) {
  __bf16 h = (__bf16)f;
  return __builtin_bit_cast(ushort, h);
}

static __device__ __forceinline__ f32x4 mfma16(b8v a, b8v b, f32x4 c) {
  return __builtin_amdgcn_mfma_f32_16x16x32_bf16(a, b, c, 0, 0, 0);
}

// ---------- kernel 0: W -> Wt bf16 transposed [3][128][1024] ----------
__global__ __launch_bounds__(256) void wconv(const float* __restrict__ Wq,
                                             const float* __restrict__ Wk,
                                             const float* __restrict__ Wv,
                                             ushort* __restrict__ Wt) {
  __shared__ float lds[64][65];
  const int m  = blockIdx.z;
  const int c0 = blockIdx.x * 64;
  const int h0 = blockIdx.y * 64;
  const float* W = (m == 0) ? Wq : (m == 1) ? Wk : Wv;

  const int cl = threadIdx.x >> 4;
  const int h4 = (threadIdx.x & 15) * 4;
#pragma unroll
  for (int i = 0; i < 4; ++i) {
    int c = cl + i * 16;
    float4 v = *reinterpret_cast<const float4*>(W + (c0 + c) * 128 + h0 + h4);
    lds[c][h4] = v.x; lds[c][h4 + 1] = v.y;
    lds[c][h4 + 2] = v.z; lds[c][h4 + 3] = v.w;
  }
  __syncthreads();
  const int hl = threadIdx.x >> 2;
  const int cs = (threadIdx.x & 3) * 16;
  s8v o0, o1;
#pragma unroll
  for (int i = 0; i < 8; ++i) o0[i] = (short)bfu(lds[cs + i][hl]);
#pragma unroll
  for (int i = 0; i < 8; ++i) o1[i] = (short)bfu(lds[cs + 8 + i][hl]);
  ushort* dst = Wt + (m * 128 + h0 + hl) * C_DIM + c0 + cs;
  *reinterpret_cast<s8v*>(dst) = o0;
  *reinterpret_cast<s8v*>(dst + 8) = o1;
}

// ---------- kernel 1: q/k/v projection (m97-style LDS pipeline) ----------
// grid (256, 3) x 256 thr (4 waves). Block tile: 32 rows x 128 cols, BK=64.
// B staged via global_load_lds (linear LDS + pre-swizzled global source,
// swizzled ds_read). A reg-staged f32->bf16 into padded LDS (T14 split).
__global__ __launch_bounds__(256) void proj(const float* __restrict__ x,
                                            const ushort* __restrict__ Wt,
                                            ushort* __restrict__ q,
                                            ushort* __restrict__ k,
                                            ushort* __restrict__ vt) {
  __shared__ __align__(16) ushort Ab[2][32 * 72];    // 4608 B each, padded
  __shared__ __align__(16) ushort Bb[2][128 * 64];   // 16 KB each, swizzled
  __shared__ __align__(16) ushort stage[5120];

  const int t   = threadIdx.x;
  const int w   = t >> 6;
  const int lid = t & 63;
  const int lr  = lid & 15;
  const int g   = lid >> 4;
  const int wr  = w >> 1;   // q-row half
  const int wc  = w & 1;    // col half
  const int m   = blockIdx.y;
  const int r0  = blockIdx.x * 32;

  // A staging: thread covers row t>>3, 8 f32 at (t&7)*8
  const int arow = t >> 3;
  const int acol = (t & 7) * 8;
  const float* ag = x + (r0 + arow) * C_DIM + acol;

  // B staging: issue j covers h = j*32 + w*8 + (lid>>3); swizzled source byte
  const int bswz = (((lid & 7) ^ (lid >> 3)) << 4);
  const char* bg = (const char*)(Wt + m * 128 * C_DIM);

  f32x4 acc[4] = {};

  // ---- prologue: stage K-step 0 ----
#pragma unroll
  for (int j = 0; j < 4; ++j) {
    int h = j * 32 + w * 8 + (lid >> 3);
    glds16(bg + h * 2048 + bswz, (char*)&Bb[0][0] + j * 4096 + w * 1024);
  }
  {
    f32x8 av = *reinterpret_cast<const f32x8*>(ag);
    b8v ac = cvt8(av);
    *reinterpret_cast<s8v*>(&Ab[0][arow * 72 + acol]) =
        __builtin_bit_cast(s8v, ac);
  }
  __syncthreads();

  int cur = 0;
#pragma unroll 1
  for (int i = 0; i < 16; ++i) {
    const int nxt = cur ^ 1;
    f32x8 an;
    if (i < 15) {
      const int kk = (i + 1) * 64;
#pragma unroll
      for (int j = 0; j < 4; ++j) {
        int h = j * 32 + w * 8 + (lid >> 3);
        glds16(bg + h * 2048 + kk * 2 + bswz,
               (char*)&Bb[nxt][0] + j * 4096 + w * 1024);
      }
      an = *reinterpret_cast<const f32x8*>(ag + kk);
    }

    // ---- compute on cur ----
#pragma unroll
    for (int kk2 = 0; kk2 < 2; ++kk2) {
      b8v af = ldb8(&Ab[cur][(wr * 16 + lr) * 72 + kk2 * 32 + g * 8]);
#pragma unroll
      for (int cn = 0; cn < 4; ++cn) {
        int h = wc * 64 + cn * 16 + lr;
        int inner = (kk2 * 64 + g * 16) ^ ((h & 7) << 4);
        b8v bf = ldb8(
            (const ushort*)((const char*)&Bb[cur][h * 64] + inner));
        acc[cn] = mfma16(af, bf, acc[cn]);
      }
    }

    if (i < 15) {
      b8v anc = cvt8(an);
      *reinterpret_cast<s8v*>(&Ab[nxt][arow * 72 + acol]) =
          __builtin_bit_cast(s8v, anc);
    }
    __syncthreads();
    cur = nxt;
  }

  // ---- epilogue ----
  if (m < 2) {
#pragma unroll
    for (int cn = 0; cn < 4; ++cn)
#pragma unroll
      for (int j = 0; j < 4; ++j)
        stage[(wr * 16 + 4 * g + j) * 136 + wc * 64 + cn * 16 + lr] =
            bfu(acc[cn][j]);
    __syncthreads();
    ushort* dst = (m == 0) ? q : k;
#pragma unroll
    for (int c = 0; c < 2; ++c) {
      int chunk = c * 256 + t;  // 512 chunks of 8: 32 rows x 16
      int row = chunk >> 4, col8 = chunk & 15;
      s8v v8 = *reinterpret_cast<const s8v*>(&stage[row * 136 + col8 * 8]);
      *reinterpret_cast<s8v*>(&dst[(r0 + row) * 128 + col8 * 8]) = v8;
    }
  } else {
#pragma unroll
    for (int cn = 0; cn < 4; ++cn)
#pragma unroll
      for (int j = 0; j < 4; ++j)
        stage[(wc * 64 + cn * 16 + lr) * 40 + wr * 16 + 4 * g + j] =
            bfu(acc[cn][j]);
    __syncthreads();
    int b = blockIdx.x >> 6;
    int tbase = (blockIdx.x & 63) * 32;
#pragma unroll
    for (int c = 0; c < 2; ++c) {
      int chunk = c * 256 + t;  // 512 chunks: 128 h x 4 t-chunks
      int h = chunk >> 2, t8 = chunk & 3;
      s8v v8 = *reinterpret_cast<const s8v*>(&stage[h * 40 + t8 * 8]);
      *reinterpret_cast<s8v*>(&vt[(b * 128 + h) * T_DIM + tbase + t8 * 8]) = v8;
    }
  }
}

// ---------- kernel 2: flash attention, shared K/V via LDS pipeline ----------
// grid (64, 4): 32 q-rows per block, kv streams 0..2048 in steps of 64.
// 8 waves = (wq in {0,1}) x (wh in {0..3}).
// QK^T: wave computes 16q x 16kv (kv quarter). PV: wave computes 16q x 32h
// (h quarter) over the kv-64 tile -> O cols partitioned, only l-sums merge.
// K_lds[64][128], Vt_lds[128][64] double-buffered via global_load_lds,
// both XOR-swizzled (byte ^= (row&7)<<4). Dynamic LDS: 70400 B.
__global__ __launch_bounds__(512) void attn(const ushort* __restrict__ q,
                                            const ushort* __restrict__ k,
                                            const ushort* __restrict__ vt,
                                            float* __restrict__ out) {
  extern __shared__ __align__(16) char smem[];
  // layout: Kb[2] @0 (16384 each), Vb[2] @32768 (16384 each),
  //         pbuf @65536 ([2][16*68] ushort = 4352), lbuf @69888 ([2][4][16] f32)
  ushort* pb = (ushort*)(smem + 65536) + (threadIdx.x >> 8) * (16 * 68);
  float* lb = (float*)(smem + 69888);

  const int t   = threadIdx.x;
  const int w   = t >> 6;
  const int lid = t & 63;
  const int lr  = lid & 15;
  const int g   = lid >> 4;
  const int wq  = w >> 2;
  const int wh  = w & 3;
  const int b   = blockIdx.y;
  const int t0  = blockIdx.x * 32;

  // hoist Q fragments (wave's 16 rows x 128)
  const ushort* qp = q + (b * T_DIM + t0 + wq * 16) * 128;
  b8v aq[4];
#pragma unroll
  for (int kf = 0; kf < 4; ++kf)
    aq[kf] = ldb8(&qp[lr * 128 + kf * 32 + g * 8]);

  // staging source swizzles (lane-constant)
  const int kswz = (((lid & 15) ^ ((w & 1) * 4 + (lid >> 4))) << 4);
  const int vswz = (((lid & 7) ^ (lid >> 3)) << 4);
  const char* kgb = (const char*)(k + b * T_DIM * 128);
  const char* vgb = (const char*)(vt + b * 128 * T_DIM);

  float lsum[4] = {0.0f, 0.0f, 0.0f, 0.0f};
  f32x4 of[2] = {};
  const float scale = 0.08838834764831845f;  // 128^-0.5

  // ---- prologue: stage kv-step 0 ----
#pragma unroll
  for (int j = 0; j < 2; ++j) {
    int r = j * 32 + w * 4 + (lid >> 4);
    glds16(kgb + r * 256 + kswz, smem + j * 8192 + w * 1024);
  }
#pragma unroll
  for (int j = 0; j < 2; ++j) {
    int h = j * 64 + w * 8 + (lid >> 3);
    glds16(vgb + h * 4096 + vswz, smem + 32768 + j * 8192 + w * 1024);
  }
  __syncthreads();

  int cur = 0;
#pragma unroll 1
  for (int i = 0; i < 32; ++i) {
    const int nxt = cur ^ 1;
    if (i < 31) {
      const int kv0 = (i + 1) * 64;
#pragma unroll
      for (int j = 0; j < 2; ++j) {
        int r = j * 32 + w * 4 + (lid >> 4);
        glds16(kgb + (kv0 + r) * 256 + kswz,
               smem + nxt * 16384 + j * 8192 + w * 1024);
      }
#pragma unroll
      for (int j = 0; j < 2; ++j) {
        int h = j * 64 + w * 8 + (lid >> 3);
        glds16(vgb + h * 4096 + kv0 * 2 + vswz,
               smem + 32768 + nxt * 16384 + j * 8192 + w * 1024);
      }
    }

    const ushort* Kb = (const ushort*)(smem + cur * 16384);
    const ushort* Vb = (const ushort*)(smem + 32768 + cur * 16384);

    // ---- QK^T: 16q x 16kv ----
    f32x4 s = {};
    {
      const int r = wh * 16 + lr;
#pragma unroll
      for (int kf = 0; kf < 4; ++kf) {
        int inner = (kf * 64 + g * 16) ^ ((r & 7) << 4);
        b8v bk = ldb8((const ushort*)((const char*)&Kb[r * 128] + inner));
        s = mfma16(aq[kf], bk, s);
      }
    }

    // ---- p = exp(s*scale - 4); lsum; store to pbuf ----
#pragma unroll
    for (int j = 0; j < 4; ++j) {
      float p = __expf(s[j] * scale - 4.0f);
      lsum[j] += p;
      pb[(4 * g + j) * 68 + wh * 16 + lr] = bfu(p);
    }
    __syncthreads();

    // ---- PV: 16q x 32h over kv-64 ----
    b8v pa0 = ldb8(&pb[lr * 68 + g * 8]);
    b8v pa1 = ldb8(&pb[lr * 68 + 32 + g * 8]);
#pragma unroll
    for (int hf = 0; hf < 2; ++hf) {
      const int h = wh * 32 + hf * 16 + lr;
      int i0 = (g * 16) ^ ((h & 7) << 4);
      int i1 = (64 + g * 16) ^ ((h & 7) << 4);
      b8v v0 = ldb8((const ushort*)((const char*)&Vb[h * 64] + i0));
      b8v v1 = ldb8((const ushort*)((const char*)&Vb[h * 64] + i1));
      of[hf] = mfma16(pa0, v0, of[hf]);
      of[hf] = mfma16(pa1, v1, of[hf]);
    }
    __syncthreads();
    cur = nxt;
  }

  // ---- merge l across the 4 wh-quarters ----
#pragma unroll
  for (int j = 0; j < 4; ++j) {
    float r = lsum[j];
    r += __shfl_xor(r, 1);
    r += __shfl_xor(r, 2);
    r += __shfl_xor(r, 4);
    r += __shfl_xor(r, 8);
    lsum[j] = r;
  }
  if (lr == 0) {
#pragma unroll
    for (int j = 0; j < 4; ++j) lb[(wq * 4 + wh) * 16 + 4 * g + j] = lsum[j];
  }
  __syncthreads();

  float inv[4];
#pragma unroll
  for (int j = 0; j < 4; ++j) {
    int row = 4 * g + j;
    float l = lb[(wq * 4 + 0) * 16 + row] + lb[(wq * 4 + 1) * 16 + row] +
              lb[(wq * 4 + 2) * 16 + row] + lb[(wq * 4 + 3) * 16 + row];
    inv[j] = 1.0f / l;
  }
  float* op = out + (b * T_DIM + t0 + wq * 16) * 128;
#pragma unroll
  for (int hf = 0; hf < 2; ++hf)
#pragma unroll
    for (int j = 0; j < 4; ++j)
      op[(4 * g + j) * 128 + wh * 32 + hf * 16 + lr] = of[hf][j] * inv[j];
}

// ---------- launcher ----------
extern "C" void kernel_launch(void* const* d_in, const int* in_sizes, int n_in,
                              void* d_out, int out_size, void* d_ws,
                              size_t ws_size, hipStream_t stream) {
  const float* x  = (const float*)d_in[0];
  const float* Wk = (const float*)d_in[1];
  const float* Wq = (const float*)d_in[2];
  const float* Wv = (const float*)d_in[3];
  float* out = (float*)d_out;

  char* ws = (char*)d_ws;
  ushort* Wt  = (ushort*)ws;                       // 0.75 MB
  ushort* qb  = (ushort*)(ws + (1u << 20));        // 2 MB
  ushort* kb  = (ushort*)(ws + 3u * (1u << 20));   // 2 MB
  ushort* vtb = (ushort*)(ws + 5u * (1u << 20));   // 2 MB

  // allow >64KB dynamic LDS for attn (idempotent; host-side, capture-safe)
  (void)hipFuncSetAttribute(reinterpret_cast<const void*>(&attn),
                            hipFuncAttributeMaxDynamicSharedMemorySize, 70400);

  wconv<<<dim3(16, 2, 3), dim3(256), 0, stream>>>(Wq, Wk, Wv, Wt);
  proj<<<dim3(256, 3), dim3(256), 0, stream>>>(x, Wt, qb, kb, vtb);
  attn<<<dim3(64, 4), dim3(512), 70400, stream>>>(qb, kb, vtb, out);
}